// Round 13
// baseline (5025.306 us; speedup 1.0000x reference)
//
#include <hip/hip_runtime.h>

#define NB 4
#define NPT 32768
#define QPT 8192          // points per quarter-cloud
#define CIN 128
#define COUT 256
#define NS 2048
#define THR 512
#define PPT 16            // points per thread (QPT / THR)
#define FASTN 10          // fast-path (L2) poll rounds before agent fallback

// ws float-offset layout
#define WS_G 0            // 128*128 Gram
#define WS_FSUM 16384     // 128 column sums
#define WS_SLOT 16512     // 4 clouds x 8 slots x 256B = 2048 floats
#define WS_GSCALE 18560   // 256
#define WS_GBIAS 18816    // 256
#define WS_IDX 19072      // 8192 ints

// d_out float-offset layout
#define OUT_COORD 0
#define OUT_FEAT 24576
#define OUT_OFFS 2121728

// Established rounds 1-12:
//  * Compute is NOT the bottleneck; the ~2 us/iter floor is the exchange:
//    agent-scope atomics are serviced MEMORY-SIDE (~800 cyc each way,
//    bypass L1+L2 -- that's why they're cross-XCD correct). Poll thinning
//    (r12) confirmed the traffic theory (+7%).
//  * THIS ROUND: cut the memory-side RT when blocks are co-located.
//    Blocks {cl,cl+8,cl+16,cl+24} share an XCD under the %8 round-robin
//    (heuristic only!). Winner DUAL-STORES its tagged key: sc0 store
//    (own XCD L2, coherent for same-XCD pollers, ~200cyc) + agent store
//    (memory-side, always-correct). Pollers: per-lane 1-bit predictor --
//    try sc0 loads; if tag absent after FASTN rounds, flip permanently to
//    agent loads. Correct under ANY placement; fast iff co-located.
//  * Slot padding 256B: an L2 line is only ever dirtied by its owning
//    block's XCD -> dirty-eviction can't clobber other slots memory-side.
//    Exact-equality tag checks make stale lines (prior graph replay,
//    deterministic values) benign.
//  * Coords in LDS (96 KB; compiler never keeps them in VGPRs). dv[16] in
//    regs. WRITE ~66 MB = Gram's memory-side atomics (expected). rocprof
//    inflates spin kernels -> compare unprofiled totals.
//  * Tagged monotone key it<<48 | dbits<<15 | (32767-gidx): bigger dist
//    wins, tie -> lower index (np.argmax first-occurrence); stale values
//    lose atomicMax automatically; slot reuse at parity distance 2 safe.
__global__ __launch_bounds__(THR) void fused1(
    const float* __restrict__ coord, const float* __restrict__ feat,
    float* __restrict__ wsf, int* __restrict__ wsi,
    unsigned long long* __restrict__ slots)
{
  __shared__ float2 lxy[QPT];                 // 65536 B
  __shared__ float lz[QPT];                   // 32768 B
  __shared__ unsigned long long s_key[2];
  __shared__ float s_fs[4][128];              // colsum scratch (2 KB)

  const int bid = blockIdx.x;
  const int t = threadIdx.x;
  const bool is_fps = (bid < 32) && ((bid & 7) < 4);

  if (is_fps) {
    // ---------------- FPS: cloud cl, quarter h ----------------
    const int cl = bid & 3;
    const int h = bid >> 3;            // 0..3; {cl,cl+8,cl+16,cl+24}: one XCD (%8 heuristic)
    const int gbase = h * QPT;
    const float* xyz = coord + (size_t)cl * NPT * 3;
    int* idx_out = wsi + cl * NS;
    unsigned long long* slot = slots + (size_t)cl * 256;  // 8 slots x 32 u64 (256B)

    float dv[PPT];
#pragma unroll
    for (int j = 0; j < PPT; ++j) {
      const int l = j * THR + t;
      const int p = gbase + l;
      lxy[l] = make_float2(xyz[p * 3 + 0], xyz[p * 3 + 1]);
      lz[l] = xyz[p * 3 + 2];
      dv[j] = 1e10f;
    }
    if (t == 0) {
      if (h == 0) idx_out[0] = 0;      // every cloud writes sample 0
      s_key[0] = s_key[1] = 0ull;      // tag 0 < any it>=1
    }
    float cx = xyz[0], cy = xyz[1], cz = xyz[2];   // same-address broadcast
    __syncthreads();                   // LDS coords + s_key ready

    const int lane = t & 63;
    unsigned fastmask = 0xFu;          // per-lane predictor: partner lane on L2 path

    for (int it = 1; it < NS; ++it) {
      const int par = it & 1;
      const unsigned long long utag = (unsigned long long)it;
      float bd = -1.f;
      int bj = 0;
      // exact numpy-f32 distance: plain muls (asm blocks fma contraction),
      // (sx+sy)+sz, v_min_f32 update; argmax tracked inline (strict > keeps
      // lowest j = lowest global index within this thread's stride).
#pragma unroll
      for (int j = 0; j < PPT; ++j) {
        const int l = j * THR + t;
        const float2 xy = lxy[l];
        const float zz = lz[l];
        float dx = xy.x - cx, dy = xy.y - cy, dz = zz - cz;
        float sx = dx * dx, sy = dy * dy, sz = dz * dz;
        asm volatile("" : "+v"(sx), "+v"(sy), "+v"(sz));
        float nd = fminf(dv[j], (sx + sy) + sz);
        dv[j] = nd;
        if (nd > bd) { bd = nd; bj = j; }
      }
      const int gidx = gbase + bj * THR + t;
      // tagged monotone key: bigger dist wins, tie -> lower idx (np.argmax)
      const unsigned long long tkey =
          (utag << 48) |
          ((unsigned long long)(unsigned)__float_as_int(bd) << 15) |
          (unsigned)(32767 - gidx);
      unsigned long long wkey = tkey;
#pragma unroll
      for (int o = 32; o > 0; o >>= 1) {
        unsigned long long ok = __shfl_xor(wkey, o, 64);
        wkey = ok > wkey ? ok : wkey;
      }
      if (lane == 0) atomicMax(&s_key[par], wkey);
      __syncthreads();                 // the ONLY barrier per iter
      const unsigned long long skey = s_key[par];
      if (tkey == skey) {              // unique winner thread (gidx unique)
        unsigned long long* myslot = &slot[(par * 4 + h) * 32];
        // L2-local copy (fast for same-XCD pollers)...
        asm volatile("global_store_dwordx2 %0, %1, off sc0"
                     :: "v"(myslot), "v"(skey) : "memory");
        // ...and the always-correct memory-side copy
        __hip_atomic_store(myslot, skey,
                           __ATOMIC_RELAXED, __HIP_MEMORY_SCOPE_AGENT);
      }
      // poll: lanes 0-3 each watch one partner slot; predictive L2/agent path
      unsigned long long v = 0;
      if (lane < 4) {
        const unsigned long long* addr = &slot[(par * 4 + lane) * 32];
        bool fast = (fastmask >> lane) & 1u;
        int tries = 0;
        for (;;) {
          if (fast) {
            asm volatile("global_load_dwordx2 %0, %1, off sc0\n\t"
                         "s_waitcnt vmcnt(0)"
                         : "=v"(v) : "v"(addr) : "memory");
          } else {
            v = __hip_atomic_load(addr, __ATOMIC_RELAXED,
                                  __HIP_MEMORY_SCOPE_AGENT);
          }
          if ((v >> 48) == utag) break;
          if (fast && ++tries >= FASTN) {      // co-location falsified for
            fast = false;                      // this partner: agent forever
            fastmask &= ~(1u << lane);
          }
          __builtin_amdgcn_s_sleep(1);
        }
      }
      unsigned long long o1 = __shfl_xor(v, 1, 64);
      v = o1 > v ? o1 : v;
      unsigned long long o2 = __shfl_xor(v, 2, 64);
      v = o2 > v ? o2 : v;
      v = __shfl(v, 0, 64);            // broadcast merged winner to all lanes
      const int widx = 32767 - (int)(v & 0x7fff);
      if (h == 0 && t == 0) idx_out[it] = widx;
      cx = xyz[widx * 3 + 0];          // same-address broadcast load (L2)
      cy = xyz[widx * 3 + 1];
      cz = xyz[widx * 3 + 2];
    }
  } else {
    // non-FPS linear index: 16 fillers inside bid<32, rest from 32 up
    const int g = (bid < 32) ? ((bid >> 3) * 4 + (bid & 7) - 4) : (bid - 16);
    if (g < 128) {
      // ---------------- Gram partial: G += chunk^T chunk ----------------
      const float* fr = feat + (size_t)g * 1024 * CIN;
      const int ti = (t & 31) * 4;
      const int tj = (t >> 5) * 8;
      float acc[4][8];
#pragma unroll
      for (int a = 0; a < 4; ++a)
#pragma unroll
        for (int b2 = 0; b2 < 8; ++b2) acc[a][b2] = 0.f;
#pragma unroll 4
      for (int r = 0; r < 1024; ++r) {
        const float* rowp = fr + r * CIN;
        float4 a4 = *(const float4*)(rowp + ti);
        float4 b4 = *(const float4*)(rowp + tj);
        float4 b5 = *(const float4*)(rowp + tj + 4);
        float av[4] = {a4.x, a4.y, a4.z, a4.w};
        float bv[8] = {b4.x, b4.y, b4.z, b4.w, b5.x, b5.y, b5.z, b5.w};
#pragma unroll
        for (int a = 0; a < 4; ++a)
#pragma unroll
          for (int b2 = 0; b2 < 8; ++b2) acc[a][b2] += av[a] * bv[b2];
      }
      float* G = wsf + WS_G;
#pragma unroll
      for (int a = 0; a < 4; ++a)
#pragma unroll
        for (int b2 = 0; b2 < 8; ++b2)
          atomicAdd(&G[(ti + a) * CIN + (tj + b2)], acc[a][b2]);
    } else {
      // ---------------- column sums of feat ----------------
      const int fb = g - 128;             // 0..7
      const size_t base = (size_t)fb * 16384;
      const int c = t & 127, rg = t >> 7; // 0..3
      float s = 0.f;
      for (int r = rg; r < 16384; r += 4)
        s += feat[(base + r) * CIN + c];
      s_fs[rg][c] = s;
      __syncthreads();
      if (t < 128) {
        float v = s_fs[0][t] + s_fs[1][t] + s_fs[2][t] + s_fs[3][t];
        atomicAdd(&wsf[WS_FSUM + t], v);
      }
    }
  }
}

// mean[c] = (fsum . W[c]) / M ; E[x^2][c] = W[c]^T G W[c] / M
__global__ __launch_bounds__(128) void finalize_k(
    const float* __restrict__ W, const float* __restrict__ gamma,
    const float* __restrict__ beta, float* __restrict__ wsf)
{
  const int c = blockIdx.x, i = threadIdx.x;
  const float* G = wsf + WS_G;
  const float* fsum = wsf + WS_FSUM;
  const float* Gi = G + i * CIN;
  const float* Wc = W + c * CIN;
  float td = 0.f;
#pragma unroll 8
  for (int j = 0; j < CIN; j += 4) {
    float4 g4 = *(const float4*)(Gi + j);
    float4 w4 = *(const float4*)(Wc + j);
    td += g4.x * w4.x + g4.y * w4.y + g4.z * w4.z + g4.w * w4.w;
  }
  const float wci = Wc[i];
  float q = wci * td;
  float m = fsum[i] * wci;
#pragma unroll
  for (int o = 32; o > 0; o >>= 1) {
    q += __shfl_xor(q, o, 64);
    m += __shfl_xor(m, o, 64);
  }
  __shared__ float sq[2], sm[2];
  if ((i & 63) == 0) { sq[i >> 6] = q; sm[i >> 6] = m; }
  __syncthreads();
  if (i == 0) {
    const float inv_m = 1.f / 131072.f;
    float mean = (sm[0] + sm[1]) * inv_m;
    float e2 = (sq[0] + sq[1]) * inv_m;
    float var = e2 - mean * mean;
    float rstd = rsqrtf(var + 1e-5f);
    float gs = gamma[c] * rstd;
    wsf[WS_GSCALE + c] = gs;
    wsf[WS_GBIAS + c] = beta[c] - mean * gs;
  }
}

// recompute x rows only at sampled indices, normalize + relu, gather coords
__global__ __launch_bounds__(256) void gather_k(
    const float* __restrict__ coord, const float* __restrict__ feat,
    const float* __restrict__ W, const float* __restrict__ wsf,
    const int* __restrict__ wsi, float* __restrict__ out)
{
  const int p = blockIdx.x, t = threadIdx.x;
  const int b = p >> 11;
  const int idx = wsi[p];
  const size_t row = (size_t)b * NPT + idx;
  __shared__ float lf[CIN];
  if (t < CIN) lf[t] = feat[row * CIN + t];
  __syncthreads();
  const float* Wc = W + t * CIN;
  float acc = 0.f;
#pragma unroll 8
  for (int k = 0; k < CIN; k += 4) {
    float4 w4 = *(const float4*)(Wc + k);
    acc += lf[k] * w4.x + lf[k + 1] * w4.y + lf[k + 2] * w4.z + lf[k + 3] * w4.w;
  }
  float y = fmaxf(fmaf(acc, wsf[WS_GSCALE + t], wsf[WS_GBIAS + t]), 0.f);
  out[OUT_FEAT + (size_t)p * COUT + t] = y;
  if (t < 3) out[OUT_COORD + p * 3 + t] = coord[row * 3 + t];
  if (p == 0 && t < 4) out[OUT_OFFS + t] = (float)((t + 1) * NS);
}

extern "C" void kernel_launch(void* const* d_in, const int* in_sizes, int n_in,
                              void* d_out, int out_size, void* d_ws, size_t ws_size,
                              hipStream_t stream)
{
  const float* coord = (const float*)d_in[0];
  const float* feat  = (const float*)d_in[1];
  // d_in[2] = offset (implied by constants)
  const float* W     = (const float*)d_in[3];
  const float* gamma = (const float*)d_in[4];
  const float* beta  = (const float*)d_in[5];
  float* wsf = (float*)d_ws;
  int* wsi = (int*)(wsf + WS_IDX);
  unsigned long long* slots = (unsigned long long*)(wsf + WS_SLOT);
  float* out = (float*)d_out;

  // zero Gram + colsum accumulators AND all (padded) sync slots; stream-
  // ordered before fused1 (kills stale memory-side tags across replays)
  hipMemsetAsync(d_ws, 0, (WS_SLOT + 2048) * sizeof(float), stream);

  fused1<<<152, THR, 0, stream>>>(coord, feat, wsf, wsi, slots);
  finalize_k<<<COUT, 128, 0, stream>>>(W, gamma, beta, wsf);
  gather_k<<<NB * NS, 256, 0, stream>>>(coord, feat, W, wsf, wsi, out);
}